// Round 4
// baseline (617.363 us; speedup 1.0000x reference)
//
#include <hip/hip_runtime.h>

// Segment-mean aggregation:
//   feat_map [1, C=128, 512, 1024] f32, seg [P=524288] i32 in [0,N=400)
//   out [N, C] f32 = per-segment mean (0 for empty segments)
//
// R3 post-mortem: VGPR_Count=16 proves the compiler destroyed the register
// pipeline (guarded prefetch + launch_bounds(,8)); every round so far had ~1
// load in flight per wave -> latency-serialized at ~470 GB/s. R4 forces MLP:
// peeled register double-buffer, batches of 3 independent loads (1 seg int4 +
// 2 feat float4 channel streams), no conditionals in the steady loop,
// launch_bounds(256,4) so the allocator has ~128 VGPRs to keep both batches
// live. LDS ds_add scatter rate unchanged (discriminates vs scatter-pipe
// hypothesis).

#define NSEG 400
#define THREADS 256
#define CPB 2            // channels per block (independent feat streams)
#define UNROLL 2         // k-steps per register batch

__global__ __launch_bounds__(256)
void zero_kernel(float* __restrict__ p, int n)
{
    const int i = blockIdx.x * 256 + threadIdx.x;
    if (i < n) p[i] = 0.f;
}

__global__ __launch_bounds__(THREADS, 4)
void seg_partial_kernel(const float* __restrict__ feat,
                        const int* __restrict__ seg,
                        float* __restrict__ acc,    // [C][N] global accum
                        float* __restrict__ cnt,    // [N]
                        long P, int N, int kIters)
{
    __shared__ float s_sum[CPB][NSEG];
    __shared__ int   s_cnt[NSEG];

    const int tid = threadIdx.x;
    const int g   = blockIdx.x;       // channel-pair index
    const int w   = blockIdx.y;       // pixel window
    const int c0  = g * CPB;
    const bool doCnt = (g == 0);

    for (int i = tid; i < CPB * NSEG; i += THREADS) (&s_sum[0][0])[i] = 0.f;
    for (int i = tid; i < NSEG; i += THREADS) s_cnt[i] = 0;
    __syncthreads();

    const long pbase = (long)w * kIters * (THREADS * 4);
    const int*   sp  = seg  + pbase + (long)tid * 4;
    const float* fp0 = feat + (long)c0 * P + pbase + (long)tid * 4;
    const float* fp1 = fp0 + P;

    // Register double-buffer: while consuming batch b, batch b+1's 6 loads
    // are in flight. No branches between issue and use.
    int4   sq[2][UNROLL];
    float4 v0[2][UNROLL], v1[2][UNROLL];

#define LOAD_BATCH(buf, kbase)                                          \
    _Pragma("unroll")                                                   \
    for (int u = 0; u < UNROLL; ++u) {                                  \
        const long off = (long)((kbase) + u) * (THREADS * 4);           \
        sq[buf][u] = *(const int4*)(sp + off);                          \
        v0[buf][u] = *(const float4*)(fp0 + off);                       \
        v1[buf][u] = *(const float4*)(fp1 + off);                       \
    }

#define CONSUME(buf)                                                    \
    _Pragma("unroll")                                                   \
    for (int u = 0; u < UNROLL; ++u) {                                  \
        const int4 s4 = sq[buf][u];                                     \
        const float4 a = v0[buf][u], b2 = v1[buf][u];                   \
        unsafeAtomicAdd(&s_sum[0][s4.x], a.x);                          \
        unsafeAtomicAdd(&s_sum[0][s4.y], a.y);                          \
        unsafeAtomicAdd(&s_sum[0][s4.z], a.z);                          \
        unsafeAtomicAdd(&s_sum[0][s4.w], a.w);                          \
        unsafeAtomicAdd(&s_sum[1][s4.x], b2.x);                         \
        unsafeAtomicAdd(&s_sum[1][s4.y], b2.y);                         \
        unsafeAtomicAdd(&s_sum[1][s4.z], b2.z);                         \
        unsafeAtomicAdd(&s_sum[1][s4.w], b2.w);                         \
        if (doCnt) {                                                    \
            atomicAdd(&s_cnt[s4.x], 1);                                 \
            atomicAdd(&s_cnt[s4.y], 1);                                 \
            atomicAdd(&s_cnt[s4.z], 1);                                 \
            atomicAdd(&s_cnt[s4.w], 1);                                 \
        }                                                               \
    }

    const int nb = kIters / UNROLL;
    LOAD_BATCH(0, 0)
    for (int b = 0; b < nb - 1; ++b) {
        const int cur = b & 1, nxt = cur ^ 1;
        LOAD_BATCH(nxt, (b + 1) * UNROLL)
        CONSUME(cur)
    }
    CONSUME((nb - 1) & 1)
#undef LOAD_BATCH
#undef CONSUME
    __syncthreads();

    // Flush partials to a 206 KB L2-resident accumulator (native global
    // fp32 atomics; 32-way contention max per address).
    for (int i = tid; i < CPB * N; i += THREADS) {
        const int dc = i / N;
        const int s  = i - dc * N;
        unsafeAtomicAdd(&acc[(long)(c0 + dc) * N + s], s_sum[dc][s]);
    }
    if (doCnt) {
        for (int s = tid; s < N; s += THREADS)
            unsafeAtomicAdd(&cnt[s], (float)s_cnt[s]);
    }
}

__global__ __launch_bounds__(256)
void seg_finalize_kernel(const float* __restrict__ acc,
                         const float* __restrict__ cnt,
                         float* __restrict__ out, int N, int C)
{
    const int t = blockIdx.x * 256 + threadIdx.x;
    if (t >= N * C) return;
    const int s = t / C;
    const int c = t - s * C;
    const float ct = cnt[s];
    out[t] = (ct > 0.f) ? acc[(long)c * N + s] / ct : 0.f;   // coalesced store
}

extern "C" void kernel_launch(void* const* d_in, const int* in_sizes, int n_in,
                              void* d_out, int out_size, void* d_ws, size_t ws_size,
                              hipStream_t stream)
{
    const float* feat = (const float*)d_in[0];
    const int*   seg  = (const int*)d_in[1];
    float*       out  = (float*)d_out;

    const long P = in_sizes[1];             // 524288
    const int  C = (int)(in_sizes[0] / P);  // 128
    const int  N = out_size / C;            // 400

    // Windows: want grid ~2048 blocks and kIters divisible by UNROLL.
    int W = 32;
    while (W > 1 && ((P % ((long)W * THREADS * 4)) != 0 ||
                     (P / ((long)W * THREADS * 4)) % UNROLL != 0))
        W >>= 1;
    const int kIters = (int)(P / ((long)W * THREADS * 4));   // 16

    float* acc = (float*)d_ws;              // C*N floats
    float* cnt = acc + (size_t)C * N;       // N floats

    const int nz = C * N + N;
    zero_kernel<<<(nz + 255) / 256, 256, 0, stream>>>(acc, nz);

    seg_partial_kernel<<<dim3(C / CPB, W), dim3(THREADS), 0, stream>>>(
        feat, seg, acc, cnt, P, N, kIters);

    seg_finalize_kernel<<<(N * C + 255) / 256, 256, 0, stream>>>(
        acc, cnt, out, N, C);
}

// Round 5
// 555.529 us; speedup vs baseline: 1.1113x; 1.1113x over previous
//
#include <hip/hip_runtime.h>

// Segment-mean aggregation:
//   feat_map [1, C=128, 512, 1024] f32, seg [P=524288] i32 in [0,N=400)
//   out [N, C] f32 = per-segment mean (0 for empty segments)
//
// R1-R4 post-mortem: time invariant at ~354 us across wildly different
// structures; the constant is 4096 LDS scatter-atomic wave-instrs per CU at
// ~207 cyc each (~3.2 cyc/lane, per-lane-serialized atomic unit). Fix:
// REMOVE the per-element scatter-atomic. R5 sorts pixels by segment
// (histogram -> scan -> ranked scatter-write of bf16 channel-rows, only
// P/64 = 8192 int-atomic instrs total), then reduces each segment's
// contiguous slice with plain coalesced loads + register adds (0 atomics).

#define NSEG_MAX 512
#define C_FAST   128
#define C2       (C_FAST / 2)   // 64 packed-bf16 uints per pixel row
#define PXW      128            // pixels per scatter block
#define LROW     67             // LDS tile row stride in uints (bank pad)

// ---------------- fast path ----------------

__global__ __launch_bounds__(512)
void k0_zero(int* __restrict__ cnt, int n)
{
    const int t = threadIdx.x;
    if (t < n) cnt[t] = 0;
}

__global__ __launch_bounds__(256)
void k1_hist(const int* __restrict__ seg, int* __restrict__ cnt, int N)
{
    __shared__ int h[NSEG_MAX];
    const int t = threadIdx.x;
    for (int i = t; i < N; i += 256) h[i] = 0;
    __syncthreads();
    const long base = (long)blockIdx.x * 1024 + t * 4;
    const int4 s4 = *(const int4*)(seg + base);
    atomicAdd(&h[s4.x], 1); atomicAdd(&h[s4.y], 1);
    atomicAdd(&h[s4.z], 1); atomicAdd(&h[s4.w], 1);
    __syncthreads();
    for (int i = t; i < N; i += 256)
        if (h[i]) atomicAdd(&cnt[i], h[i]);
}

__global__ __launch_bounds__(NSEG_MAX)
void k2_scan(const int* __restrict__ cnt, int* __restrict__ offs,
             int* __restrict__ cursor, int N)
{
    __shared__ int a[NSEG_MAX];
    const int t = threadIdx.x;
    const int v = (t < N) ? cnt[t] : 0;
    a[t] = v;
    __syncthreads();
    for (int off = 1; off < NSEG_MAX; off <<= 1) {
        const int x = (t >= off) ? a[t - off] : 0;
        __syncthreads();
        a[t] += x;
        __syncthreads();
    }
    if (t < N) { const int e = a[t] - v; offs[t] = e; cursor[t] = e; }
}

__device__ __forceinline__ unsigned pk_bf16(float lo, float hi)
{
    unsigned a = __builtin_bit_cast(unsigned, lo);
    unsigned b = __builtin_bit_cast(unsigned, hi);
    a += 0x7FFFu + ((a >> 16) & 1u);     // RNE
    b += 0x7FFFu + ((b >> 16) & 1u);
    return (a >> 16) | (b & 0xFFFF0000u);
}

// Stream feat (coalesced), LDS-transpose to pixel-major bf16 rows, rank each
// pixel via one int atomic, store 256 B rows to fs[rank]. No FP atomics.
__global__ __launch_bounds__(256)
void k3_scatter(const float* __restrict__ feat, const int* __restrict__ seg,
                int* __restrict__ cursor, unsigned* __restrict__ fs, long P)
{
    __shared__ unsigned tile[PXW * LROW];   // [px][c2], padded rows
    __shared__ int srank[PXW];

    const int tid = threadIdx.x;
    const long p0 = (long)blockIdx.x * PXW;
    const int l = tid & 31, r = tid >> 5;            // 32 lanes x 8 rows

    // Phase A: [c][px] coalesced reads -> bf16-packed [px][c2] LDS tile.
    #pragma unroll
    for (int it = 0; it < 8; ++it) {
        const int c2 = it * 8 + r;                   // covers 0..63
        const float* f0 = feat + (long)(2 * c2) * P + p0 + l * 4;
        const float4 va = *(const float4*)(f0);      // channel 2*c2
        const float4 vb = *(const float4*)(f0 + P);  // channel 2*c2+1
        unsigned* tr = tile + c2;
        const int pxb = 4 * l;
        tr[(pxb + 0) * LROW] = pk_bf16(va.x, vb.x);
        tr[(pxb + 1) * LROW] = pk_bf16(va.y, vb.y);
        tr[(pxb + 2) * LROW] = pk_bf16(va.z, vb.z);
        tr[(pxb + 3) * LROW] = pk_bf16(va.w, vb.w);
    }
    if (tid < PXW) {
        const int s = seg[p0 + tid];
        srank[tid] = atomicAdd(&cursor[s], 1);       // int atomic, native
    }
    __syncthreads();

    // Phase B: each wave stores rows (64 lanes = full 256 B row, coalesced).
    const int wave = tid >> 6, wl = tid & 63;
    for (int px = wave; px < PXW; px += 4) {
        const unsigned u = tile[px * LROW + wl];     // 2-way banks: free
        fs[(long)srank[px] * C2 + wl] = u;
    }
}

// Block per segment: contiguous coalesced reads, register accumulate, 0 atomics.
__global__ __launch_bounds__(512)
void k4_reduce(const unsigned* __restrict__ fs, const int* __restrict__ offs,
               const int* __restrict__ cnt, float* __restrict__ out)
{
    __shared__ float red[8][C_FAST];
    const int s = blockIdx.x;
    const int tid = threadIdx.x, l = tid & 63, j = tid >> 6;   // j 0..7
    const int start = offs[s], n = cnt[s];

    float a0 = 0.f, a1 = 0.f;
    const unsigned* base = fs + (long)start * C2 + l;
    for (int i = j; i < n; i += 8) {                 // 8 rows in flight/block
        const unsigned u = base[(long)i * C2];
        a0 += __builtin_bit_cast(float, u << 16);            // channel 2l
        a1 += __builtin_bit_cast(float, u & 0xFFFF0000u);    // channel 2l+1
    }
    red[j][2 * l]     = a0;
    red[j][2 * l + 1] = a1;
    __syncthreads();
    if (tid < C_FAST) {
        float sum = 0.f;
        #pragma unroll
        for (int q = 0; q < 8; ++q) sum += red[q][tid];
        out[(long)s * C_FAST + tid] = (n > 0) ? sum / (float)n : 0.f;
    }
}

// ---------------- fallback path (R4, known-correct) ----------------

#define FB_THREADS 256
#define FB_CPB 2

__global__ __launch_bounds__(256)
void fb_zero(float* __restrict__ p, int n)
{
    const int i = blockIdx.x * 256 + threadIdx.x;
    if (i < n) p[i] = 0.f;
}

__global__ __launch_bounds__(FB_THREADS, 4)
void fb_partial(const float* __restrict__ feat, const int* __restrict__ seg,
                float* __restrict__ acc, float* __restrict__ cnt,
                long P, int N, int kIters)
{
    __shared__ float s_sum[FB_CPB][NSEG_MAX];
    __shared__ int   s_cnt[NSEG_MAX];
    const int tid = threadIdx.x;
    const int g = blockIdx.x, w = blockIdx.y;
    const int c0 = g * FB_CPB;
    const bool doCnt = (g == 0);
    for (int i = tid; i < FB_CPB * NSEG_MAX; i += FB_THREADS) (&s_sum[0][0])[i] = 0.f;
    for (int i = tid; i < NSEG_MAX; i += FB_THREADS) s_cnt[i] = 0;
    __syncthreads();
    const long pbase = (long)w * kIters * (FB_THREADS * 4);
    const int*   sp  = seg + pbase + (long)tid * 4;
    const float* fp0 = feat + (long)c0 * P + pbase + (long)tid * 4;
    const float* fp1 = fp0 + P;
    for (int k = 0; k < kIters; ++k) {
        const long off = (long)k * (FB_THREADS * 4);
        const int4 s4 = *(const int4*)(sp + off);
        const float4 a = *(const float4*)(fp0 + off);
        const float4 b = *(const float4*)(fp1 + off);
        unsafeAtomicAdd(&s_sum[0][s4.x], a.x);
        unsafeAtomicAdd(&s_sum[0][s4.y], a.y);
        unsafeAtomicAdd(&s_sum[0][s4.z], a.z);
        unsafeAtomicAdd(&s_sum[0][s4.w], a.w);
        unsafeAtomicAdd(&s_sum[1][s4.x], b.x);
        unsafeAtomicAdd(&s_sum[1][s4.y], b.y);
        unsafeAtomicAdd(&s_sum[1][s4.z], b.z);
        unsafeAtomicAdd(&s_sum[1][s4.w], b.w);
        if (doCnt) {
            atomicAdd(&s_cnt[s4.x], 1); atomicAdd(&s_cnt[s4.y], 1);
            atomicAdd(&s_cnt[s4.z], 1); atomicAdd(&s_cnt[s4.w], 1);
        }
    }
    __syncthreads();
    for (int i = tid; i < FB_CPB * N; i += FB_THREADS) {
        const int dc = i / N, s = i - dc * N;
        unsafeAtomicAdd(&acc[(long)(c0 + dc) * N + s], s_sum[dc][s]);
    }
    if (doCnt)
        for (int s = tid; s < N; s += FB_THREADS)
            unsafeAtomicAdd(&cnt[s], (float)s_cnt[s]);
}

__global__ __launch_bounds__(256)
void fb_finalize(const float* __restrict__ acc, const float* __restrict__ cnt,
                 float* __restrict__ out, int N, int C)
{
    const int t = blockIdx.x * 256 + threadIdx.x;
    if (t >= N * C) return;
    const int s = t / C, c = t - s * C;
    const float ct = cnt[s];
    out[t] = (ct > 0.f) ? acc[(long)c * N + s] / ct : 0.f;
}

// ---------------- launch ----------------

extern "C" void kernel_launch(void* const* d_in, const int* in_sizes, int n_in,
                              void* d_out, int out_size, void* d_ws, size_t ws_size,
                              hipStream_t stream)
{
    const float* feat = (const float*)d_in[0];
    const int*   seg  = (const int*)d_in[1];
    float*       out  = (float*)d_out;

    const long P = in_sizes[1];             // 524288
    const int  C = (int)(in_sizes[0] / P);  // 128
    const int  N = out_size / C;            // 400

    const size_t need = (size_t)P * C2 * sizeof(unsigned) + 3u * NSEG_MAX * sizeof(int);
    const bool fast = (C == C_FAST) && (N <= NSEG_MAX) &&
                      (P % PXW == 0) && (P % 1024 == 0) && ws_size >= need;

    if (fast) {
        unsigned* fs  = (unsigned*)d_ws;                 // [P][C2] bf16-pairs
        int* cnt    = (int*)(fs + (size_t)P * C2);
        int* offs   = cnt + NSEG_MAX;
        int* cursor = offs + NSEG_MAX;

        k0_zero  <<<1, 512, 0, stream>>>(cnt, N);
        k1_hist  <<<(int)(P / 1024), 256, 0, stream>>>(seg, cnt, N);
        k2_scan  <<<1, NSEG_MAX, 0, stream>>>(cnt, offs, cursor, N);
        k3_scatter<<<(int)(P / PXW), 256, 0, stream>>>(feat, seg, cursor, fs, P);
        k4_reduce<<<N, 512, 0, stream>>>(fs, offs, cnt, out);
    } else {
        // R4 fallback (LDS-atomic scatter) — correct, ~615 us.
        int W = 32;
        while (W > 1 && (P % ((long)W * FB_THREADS * 4)) != 0) W >>= 1;
        const int kIters = (int)(P / ((long)W * FB_THREADS * 4));
        float* acc = (float*)d_ws;
        float* cnt = acc + (size_t)C * N;
        const int nz = C * N + N;
        fb_zero<<<(nz + 255) / 256, 256, 0, stream>>>(acc, nz);
        fb_partial<<<dim3(C / FB_CPB, W), dim3(FB_THREADS), 0, stream>>>(
            feat, seg, acc, cnt, P, N, kIters);
        fb_finalize<<<(N * C + 255) / 256, 256, 0, stream>>>(acc, cnt, out, N, C);
    }
}